// Round 16
// baseline (439.140 us; speedup 1.0000x reference)
//
#include <hip/hip_runtime.h>
#include <math.h>

#define BN    2456
#define LSEQ  12
#define DM    128
#define NODES 307
#define MROWS 29472   // BN * LSEQ
#define FREQ_BLKS  1228
#define FUSED2_BLKS 480   // 96 (b,l) x 5 tiles of 64 nodes

typedef __bf16 bfx8 __attribute__((ext_vector_type(8)));
typedef __bf16 bfx4 __attribute__((ext_vector_type(4)));
typedef float  f32x4 __attribute__((ext_vector_type(4)));

#define MFMA16(a, b, c) __builtin_amdgcn_mfma_f32_16x16x32_bf16(a, b, c, 0, 0, 0)

__device__ __forceinline__ float fsilu(float v)     { return v / (1.0f + __expf(-v)); }
__device__ __forceinline__ float fsoftplus(float x) { return fmaxf(x, 0.f) + __logf(1.0f + __expf(-fabsf(x))); }

// ---------------- K0: convert + pre-swizzle weights into MFMA fragment order ----------------
__global__ __launch_bounds__(256)
void k_convert(const float* __restrict__ in_w, const float* __restrict__ x_w,
               const float* __restrict__ dt_w, const float* __restrict__ out_w,
               const float* __restrict__ graph,
               const float* __restrict__ fw_r, const float* __restrict__ fw_i,
               __bf16* __restrict__ in_w_sw, __bf16* __restrict__ x_w_sw,
               __bf16* __restrict__ dtw_sw, __bf16* __restrict__ out_w_sw,
               __bf16* __restrict__ graph_sw, float* __restrict__ mw) {
    int idx = blockIdx.x * 256 + threadIdx.x;
    if (idx < 131072) {            // in_w: 4e x 16nt x 4kc (K=128)
        int o = idx;
        int e = o >> 15, r = o & 32767;
        int frag = r >> 9, lane = (r >> 3) & 63, j = r & 7;
        int nt = frag >> 2, kc = frag & 3, lm = lane & 15, lq = lane >> 4;
        in_w_sw[o] = (__bf16)in_w[e * 32768 + (nt * 16 + lm) * 128 + kc * 32 + lq * 8 + j];
        return;
    }
    idx -= 131072;
    if (idx < 98304) {             // x_w: 4e x 12nt x 4kc (K=128)
        int o = idx;
        int e = o / 24576, r = o - e * 24576;
        int frag = r >> 9, lane = (r >> 3) & 63, j = r & 7;
        int nt = frag >> 2, kc = frag & 3, lm = lane & 15, lq = lane >> 4;
        x_w_sw[o] = (__bf16)x_w[e * 24576 + (nt * 16 + lm) * 128 + kc * 32 + lq * 8 + j];
        return;
    }
    idx -= 98304;
    if (idx < 16384) {             // dt_w: 4e x 8nt (K=32)
        int o = idx;
        int e = o >> 12, r = o & 4095;
        int nt = r >> 9, lane = (r >> 3) & 63, j = r & 7;
        int lm = lane & 15, lq = lane >> 4;
        dtw_sw[o] = (__bf16)dt_w[e * 4096 + (nt * 16 + lm) * 32 + lq * 8 + j];
        return;
    }
    idx -= 16384;
    if (idx < 65536) {             // out_w: 4e x 8nt x 4kc (K=128)
        int o = idx;
        int e = o >> 14, r = o & 16383;
        int frag = r >> 9, lane = (r >> 3) & 63, j = r & 7;
        int f = frag >> 2, kc = frag & 3, lm = lane & 15, lq = lane >> 4;
        out_w_sw[o] = (__bf16)out_w[e * 16384 + (f * 16 + lm) * 128 + kc * 32 + lq * 8 + j];
        return;
    }
    idx -= 65536;
    if (idx < 1572864) {           // graph: coalesced read, fragment-order write
        int bl = idx >> 14, r = idx & 16383;
        int dd = r >> 7, a = r & 127;           // src: graph[bl][dd][a], B rows=K=dd, cols=a
        int nt = a >> 4, lm = a & 15, kc = dd >> 5, lq = (dd >> 3) & 3, j = dd & 7;
        graph_sw[(size_t)bl * 16384 + ((size_t)((nt * 4 + kc) * 64 + lq * 16 + lm)) * 8 + j] =
            (__bf16)graph[(size_t)bl * 16384 + dd * 128 + a];
        return;
    }
    idx -= 1572864;
    if (idx < 336) {               // M = fw[:, :13] . D24  (7x12 complex per expert)
        int o = idx;
        int e = o / 84, r = o - e * 84;
        int o2 = r / 12, l = r - o2 * 12;
        float mr = 0.f, mi = 0.f;
        for (int k = 0; k < 13; ++k) {
            float sv, cv;
            __sincosf(6.283185307179586f * (float)(k * l) / 24.0f, &sv, &cv);
            const float wr = fw_r[e * 133 + o2 * 19 + k], wi = fw_i[e * 133 + o2 * 19 + k];
            mr += wr * cv + wi * sv;
            mi += wi * cv - wr * sv;
        }
        mw[e * 256 + (o2 * 12 + l) * 2]     = mr;
        mw[e * 256 + (o2 * 12 + l) * 2 + 1] = mi;
        return;
    }
    idx -= 336;
    if (idx < 168) {               // w2 copy (7x6 complex per expert)
        int o = idx;
        int e = o / 42, r = o - e * 42;
        int o2 = r / 6, k = r - o2 * 6;
        mw[e * 256 + 168 + (o2 * 6 + k) * 2]     = fw_r[e * 133 + o2 * 19 + 13 + k];
        mw[e * 256 + 168 + (o2 * 6 + k) * 2 + 1] = fw_i[e * 133 + o2 * 19 + 13 + k];
    }
}

// ---------------- K1: {freq rows FIRST} + {fused 64-node GEMM tiles after} ----------------
// Fused path: wave w owns 16 nodes; phases chain on wave-private SoA LDS (no barriers).
// Phase 5 assembles the AoS scanp tile (dl,xs,dp,sz per d) and writes it with
// one fully-coalesced 1KB wave store per node -> each AoS line written exactly once.
__global__ __launch_bounds__(256)
void k_fused(const float* __restrict__ xcur, const float* __restrict__ norm_w,
             const __bf16* __restrict__ WiSw, const float* __restrict__ in_b,
             const __bf16* __restrict__ WxSw, const __bf16* __restrict__ DWSw,
             const float* __restrict__ dt_b, const __bf16* __restrict__ GSw,
             const float* __restrict__ mw,
             __bf16* __restrict__ scanp, float* __restrict__ bcf32,
             __bf16* __restrict__ xfq_bf, int e) {
    const int tid = threadIdx.x;
    __shared__ __bf16 sxs[4 * 16 * 136];      // xs (kept until dump)
    __shared__ __bf16 sdl[4 * 16 * 136];      // delta, then dmix
    __shared__ __bf16 ssz[4 * 16 * 128];      // sz
    __shared__ __bf16 sdp[4 * 16 * 128];      // dp
    __shared__ __bf16 sdel32[4 * 16 * 40];

    if (blockIdx.x < FREQ_BLKS) {
        // ================== freq path: 2 rows per block ==================
        float (*sred2)[2][12] = (float (*)[2][12])sxs;
        const int hh = tid >> 7, t7 = tid & 127;
        const int lane = tid & 63, w2 = (tid >> 6) & 1;
        const int row = blockIdx.x * 2 + hh;
        const int b = row / NODES, n = row - b * NODES;

        constexpr float SQ32 = 0.8660254037844386f;
        constexpr float C12[12] = {1.f, SQ32, 0.5f, 0.f, -0.5f, -SQ32, -1.f, -SQ32, -0.5f, 0.f, 0.5f, SQ32};
        constexpr float S12[12] = {0.f, 0.5f, SQ32, 1.f, SQ32, 0.5f, 0.f, -0.5f, -SQ32, -1.f, -SQ32, -0.5f};

        const float* xp = xcur + (size_t)row * 1536 + t7;
        float xv[12], v[12];
#pragma unroll
        for (int l = 0; l < 12; ++l) { xv[l] = xp[l * 128]; v[l] = xv[l] * xv[l]; }
#pragma unroll
        for (int off = 32; off; off >>= 1)
#pragma unroll
            for (int i = 0; i < 12; ++i) v[i] += __shfl_xor(v[i], off, 64);
        if (lane == 0) {
#pragma unroll
            for (int i = 0; i < 12; ++i) sred2[hh][w2][i] = v[i];
        }
        __syncthreads();
#pragma unroll
        for (int i = 0; i < 12; ++i) v[i] = sred2[hh][0][i] + sred2[hh][1][i];
        __syncthreads();

        const float nrmw = norm_w[e * DM + t7];
        float xnr[12];
#pragma unroll
        for (int l = 0; l < 12; ++l)
            xnr[l] = xv[l] * rsqrtf(v[l] * (1.0f / 128.0f) + 1e-5f) * nrmw;

        float fr[7], fi[7];
#pragma unroll
        for (int o2 = 0; o2 < 7; ++o2) {
            float r = 0.f, im = 0.f;
#pragma unroll
            for (int l = 0; l < 12; ++l) {
                const int t = (o2 * l) % 12;
                r += xnr[l] * C12[t];
                im -= xnr[l] * S12[t];
            }
            fr[o2] = r; fi[o2] = im;
        }

        float a7[7];
#pragma unroll
        for (int o2 = 0; o2 < 7; ++o2) {
            const float ar = fr[o2] + 1e-6f, ai = fi[o2] + 1e-6f;
            a7[o2] = ar * ar + ai * ai;
        }
#pragma unroll
        for (int pss = 0; pss < 6; ++pss)
#pragma unroll
            for (int j = 0; j < 6; ++j) {
                const float hi = fmaxf(a7[j], a7[j + 1]);
                const float lo = fminf(a7[j], a7[j + 1]);
                a7[j] = hi; a7[j + 1] = lo;
            }

        const float* Me = mw + e * 256;
        float p7[7];
#pragma unroll
        for (int o2 = 0; o2 < 7; ++o2) {
            float pr = 0.f, pi = 0.f;
#pragma unroll
            for (int l = 0; l < 12; ++l) {
                pr += xnr[l] * Me[(o2 * 12 + l) * 2];
                pi += xnr[l] * Me[(o2 * 12 + l) * 2 + 1];
            }
#pragma unroll
            for (int k = 0; k < 6; ++k) {
                pr += a7[k] * Me[168 + (o2 * 6 + k) * 2];
                pi += a7[k] * Me[168 + (o2 * 6 + k) * 2 + 1];
            }
            p7[o2] = pr * pr + pi * pi;
        }

        float m7[7];
#pragma unroll
        for (int i = 0; i < 7; ++i) m7[i] = p7[i];
#pragma unroll
        for (int off = 32; off; off >>= 1)
#pragma unroll
            for (int i = 0; i < 7; ++i) m7[i] = fmaxf(m7[i], __shfl_xor(m7[i], off, 64));
        if (lane == 0) {
#pragma unroll
            for (int i = 0; i < 7; ++i) sred2[hh][w2][i] = m7[i];
        }
        __syncthreads();
#pragma unroll
        for (int i = 0; i < 7; ++i) m7[i] = fmaxf(sred2[hh][0][i], sred2[hh][1][i]);
        __syncthreads();

        float ex[7], sm[7];
#pragma unroll
        for (int i = 0; i < 7; ++i) { ex[i] = __expf(p7[i] - m7[i]); sm[i] = ex[i]; }
#pragma unroll
        for (int off = 32; off; off >>= 1)
#pragma unroll
            for (int i = 0; i < 7; ++i) sm[i] += __shfl_xor(sm[i], off, 64);
        if (lane == 0) {
#pragma unroll
            for (int i = 0; i < 7; ++i) sred2[hh][w2][i] = sm[i];
        }
        __syncthreads();
#pragma unroll
        for (int i = 0; i < 7; ++i) sm[i] = sred2[hh][0][i] + sred2[hh][1][i];

        float gr[7], gi[7];
#pragma unroll
        for (int o2 = 0; o2 < 7; ++o2) {
            const float wf = ex[o2] / sm[o2];
            gr[o2] = wf * fr[o2];
            gi[o2] = wf * fi[o2];
        }

        const size_t xb = ((size_t)(b * 12) * NODES + n) * 128 + t7;
#pragma unroll
        for (int l = 0; l < 12; ++l) {
            float val = gr[0] + ((l & 1) ? -gr[6] : gr[6]);
#pragma unroll
            for (int o2 = 1; o2 < 6; ++o2) {
                const int t = (o2 * l) % 12;
                val += 2.0f * (gr[o2] * C12[t] - gi[o2] * S12[t]);
            }
            xfq_bf[xb + (size_t)l * (NODES * 128)] = (__bf16)(val * (1.0f / 12.0f));
        }
        return;
    }

    // ================== fused GEMM path: (b,l) x 64 nodes, m-split waves ==================
    const int fid = blockIdx.x - FREQ_BLKS;      // 0..479
    const int bl = fid / 5;
    const int n0 = (fid - bl * 5) * 64;
    const int wave = tid >> 6, lane = tid & 63;
    const int lm = lane & 15, lq = lane >> 4;
    const int b = bl / 12, l = bl - b * 12;
    const int nbase = n0 + wave * 16;            // this wave's first node
    const size_t rowbase = (size_t)bl * NODES + nbase;
    __bf16* sxsW = sxs + wave * 16 * 136;
    __bf16* sdlW = sdl + wave * 16 * 136;
    __bf16* sszW = ssz + wave * 16 * 128;
    __bf16* sdpW = sdp + wave * 16 * 128;
    __bf16* sdel32W = sdel32 + wave * 16 * 40;

    // ---- phase 0: rmsnorm -> A fragments ----
    const int ng = min(nbase + lm, NODES - 1);
    const float* xrow = xcur + ((size_t)(b * NODES + ng) * 12 + l) * 128 + lq * 8;
    float xv[4][8];
#pragma unroll
    for (int kc = 0; kc < 4; ++kc) {
        float4 p0 = *(const float4*)(xrow + kc * 32);
        float4 p1 = *(const float4*)(xrow + kc * 32 + 4);
        xv[kc][0] = p0.x; xv[kc][1] = p0.y; xv[kc][2] = p0.z; xv[kc][3] = p0.w;
        xv[kc][4] = p1.x; xv[kc][5] = p1.y; xv[kc][6] = p1.z; xv[kc][7] = p1.w;
    }
    float ss = 0.f;
#pragma unroll
    for (int kc = 0; kc < 4; ++kc)
#pragma unroll
        for (int j = 0; j < 8; ++j) ss += xv[kc][j] * xv[kc][j];
    ss += __shfl_xor(ss, 16, 64);
    ss += __shfl_xor(ss, 32, 64);
    const float rms = rsqrtf(ss * (1.0f / 128.0f) + 1e-5f);

    bfx8 af[4];
    const float* nwp = norm_w + e * DM + lq * 8;
#pragma unroll
    for (int kc = 0; kc < 4; ++kc) {
        float4 w0 = *(const float4*)(nwp + kc * 32);
        float4 w1 = *(const float4*)(nwp + kc * 32 + 4);
        af[kc][0] = (__bf16)(xv[kc][0] * rms * w0.x);
        af[kc][1] = (__bf16)(xv[kc][1] * rms * w0.y);
        af[kc][2] = (__bf16)(xv[kc][2] * rms * w0.z);
        af[kc][3] = (__bf16)(xv[kc][3] * rms * w0.w);
        af[kc][4] = (__bf16)(xv[kc][4] * rms * w1.x);
        af[kc][5] = (__bf16)(xv[kc][5] * rms * w1.y);
        af[kc][6] = (__bf16)(xv[kc][6] * rms * w1.z);
        af[kc][7] = (__bf16)(xv[kc][7] * rms * w1.w);
    }

    const __bf16* WiP = WiSw + (size_t)e * 32768;
    const f32x4 z4 = {0.f, 0.f, 0.f, 0.f};

    // ---- phase 1a: in_proj cols 0..127 (xs -> sxsW) ----
    {
        f32x4 acc8[8];
#pragma unroll
        for (int ntl = 0; ntl < 8; ++ntl) acc8[ntl] = z4;
#pragma unroll
        for (int ntl = 0; ntl < 8; ++ntl)
#pragma unroll
            for (int kc = 0; kc < 4; ++kc) {
                bfx8 bb = *(const bfx8*)(WiP + ((ntl * 4 + kc) * 64 + lane) * 8);
                acc8[ntl] = MFMA16(af[kc], bb, acc8[ntl]);
            }
#pragma unroll
        for (int ntl = 0; ntl < 8; ++ntl) {
            const int col = ntl * 16 + lm;
            const float bias = in_b[e * 256 + col];
#pragma unroll
            for (int r = 0; r < 4; ++r) {
                const int nl = lq * 4 + r;
                sxsW[nl * 136 + col] = (__bf16)fsilu(acc8[ntl][r] + bias);
            }
        }
    }
    // ---- phase 1b: in_proj cols 128..255 (z -> silu -> sszW) ----
    {
        f32x4 acc8[8];
#pragma unroll
        for (int ntl = 0; ntl < 8; ++ntl) acc8[ntl] = z4;
#pragma unroll
        for (int ntl = 0; ntl < 8; ++ntl)
#pragma unroll
            for (int kc = 0; kc < 4; ++kc) {
                bfx8 bb = *(const bfx8*)(WiP + (((ntl + 8) * 4 + kc) * 64 + lane) * 8);
                acc8[ntl] = MFMA16(af[kc], bb, acc8[ntl]);
            }
#pragma unroll
        for (int ntl = 0; ntl < 8; ++ntl) {
            const int col = ntl * 16 + lm;                 // 0..127 within z
            const float bias = in_b[e * 256 + 128 + col];
#pragma unroll
            for (int r = 0; r < 4; ++r) {
                const int nl = lq * 4 + r;
                sszW[nl * 128 + col] = (__bf16)fsilu(acc8[ntl][r] + bias);
            }
        }
    }

    // ---- phase 2: x_proj (A = wave's xs from LDS) ----
    {
        bfx8 ax[4];
#pragma unroll
        for (int kc = 0; kc < 4; ++kc)
            ax[kc] = *(const bfx8*)(sxsW + lm * 136 + kc * 32 + lq * 8);

        const __bf16* WxP = WxSw + (size_t)e * 24576;
        f32x4 acc12[12];
#pragma unroll
        for (int ntl = 0; ntl < 12; ++ntl) acc12[ntl] = z4;
#pragma unroll
        for (int ntl = 0; ntl < 12; ++ntl)
#pragma unroll
            for (int kc = 0; kc < 4; ++kc) {
                bfx8 bb = *(const bfx8*)(WxP + ((ntl * 4 + kc) * 64 + lane) * 8);
                acc12[ntl] = MFMA16(ax[kc], bb, acc12[ntl]);
            }
#pragma unroll
        for (int ntl = 0; ntl < 12; ++ntl) {
            const int col = ntl * 16 + lm;                 // 0..191
#pragma unroll
            for (int r = 0; r < 4; ++r) {
                const int nl = lq * 4 + r;
                const float v = acc12[ntl][r];
                if (col < 32) sdel32W[nl * 40 + col] = (__bf16)v;
                else if (col < 64) {
                    if ((nbase + nl) < NODES) bcf32[(rowbase + nl) * 32 + (col - 32)] = v;
                } else sdpW[nl * 128 + (col - 64)] = (__bf16)v;
            }
        }
    }

    // ---- phase 3: dt projection (K=32) -> delta into sdlW ----
    {
        bfx8 ad = *(const bfx8*)(sdel32W + lm * 40 + lq * 8);
        const __bf16* DWp = DWSw + (size_t)e * 4096;
#pragma unroll
        for (int ntl = 0; ntl < 8; ++ntl) {
            bfx8 bb = *(const bfx8*)(DWp + (ntl * 64 + lane) * 8);
            f32x4 dacc = MFMA16(ad, bb, z4);
            const int col = ntl * 16 + lm;
            const float bias = dt_b[e * 128 + col];
#pragma unroll
            for (int r = 0; r < 4; ++r) {
                const int nl = lq * 4 + r;
                sdlW[nl * 136 + col] = (__bf16)fsoftplus(dacc[r] + bias);
            }
        }
    }

    // ---- phase 4: graph mix; dmix overwrites sdlW (delta fully in ag regs first) ----
    {
        bfx8 ag[4];
#pragma unroll
        for (int kc = 0; kc < 4; ++kc)
            ag[kc] = *(const bfx8*)(sdlW + lm * 136 + kc * 32 + lq * 8);

        const __bf16* Gp = GSw + (size_t)bl * 16384;
#pragma unroll
        for (int ntl = 0; ntl < 8; ++ntl) {
            f32x4 gacc = z4;
#pragma unroll
            for (int kc = 0; kc < 4; ++kc) {
                bfx8 bb = *(const bfx8*)(Gp + ((ntl * 4 + kc) * 64 + lane) * 8);
                gacc = MFMA16(ag[kc], bb, gacc);
            }
            const int col = ntl * 16 + lm;
#pragma unroll
            for (int r = 0; r < 4; ++r) {
                const int nl = lq * 4 + r;
                sdlW[nl * 136 + col] = (__bf16)gacc[r];
            }
        }
    }

    // ---- phase 5: AoS dump -- one coalesced 1KB store per node (lane: 2 d's x 4 ch) ----
    {
        const int d0 = lane * 2, d1 = lane * 2 + 1;
#pragma unroll
        for (int nl = 0; nl < 16; ++nl) {
            if (nbase + nl >= NODES) break;
            bfx8 pkt;
            pkt[0] = sdlW[nl * 136 + d0];
            pkt[1] = sxsW[nl * 136 + d0];
            pkt[2] = sdpW[nl * 128 + d0];
            pkt[3] = sszW[nl * 128 + d0];
            pkt[4] = sdlW[nl * 136 + d1];
            pkt[5] = sxsW[nl * 136 + d1];
            pkt[6] = sdpW[nl * 128 + d1];
            pkt[7] = sszW[nl * 128 + d1];
            *(bfx8*)(scanp + (rowbase + nl) * 512 + lane * 8) = pkt;
        }
    }
}

// ---------------- K2: SSM scan + gate + out_proj + residual (round-4 exact, 24.6us) ----------------
__global__ __launch_bounds__(128)
void k_scanout(const float* __restrict__ xcur, const __bf16* __restrict__ scanp,
               const float* __restrict__ bcf32, const __bf16* __restrict__ xfq_bf,
               const float* __restrict__ A_log, const __bf16* __restrict__ WoSw,
               const float* __restrict__ out_b, const float* __restrict__ blk_w,
               const float* __restrict__ blk_b, float* __restrict__ xout, int e, int last) {
    __shared__ __bf16 s_out[16 * 136];
    const int row = blockIdx.x, tid = threadIdx.x;
    const int b = row / NODES, n = row - b * NODES;

    constexpr float LOGT[16] = {0.f, 0.6931472f, 1.0986123f, 1.3862944f, 1.6094379f, 1.7917595f,
                                1.9459101f, 2.0794415f, 2.1972246f, 2.3025851f, 2.3978953f,
                                2.4849066f, 2.5649494f, 2.6390573f, 2.7080502f, 2.7725887f};

    // ---- hoisted loads ----
    bfx4 sc12[12];
    const size_t sb = ((size_t)(b * 12) * NODES + n) * 512 + (size_t)tid * 4;
#pragma unroll
    for (int l = 0; l < 12; ++l)
        sc12[l] = *(const bfx4*)(scanp + sb + (size_t)l * (NODES * 512));

    __bf16 xq[12];
    const size_t xb = ((size_t)(b * 12) * NODES + n) * 128 + tid;
#pragma unroll
    for (int l = 0; l < 12; ++l)
        xq[l] = xfq_bf[xb + (size_t)l * (NODES * 128)];

    int chainOK = 1;
#pragma unroll
    for (int s = 0; s < 16; ++s)
        chainOK &= (fabsf(A_log[e * 16 + s] - LOGT[s]) < 1e-4f) ? 1 : 0;

#pragma unroll
    for (int r = 12; r < 16; ++r) s_out[r * 136 + tid] = (__bf16)0.f;

    float h[16];
#pragma unroll
    for (int j = 0; j < 16; ++j) h[j] = 0.f;

    if (chainOK) {
        float q1a[12];
#pragma unroll
        for (int l = 0; l < 12; ++l) q1a[l] = __expf(-(float)sc12[l][0]);
#pragma unroll
        for (int l = 0; l < 12; ++l) {
            const float dl = (float)sc12[l][0], xsv = (float)sc12[l][1];
            const float dlx = dl * xsv;
            const float* bc = bcf32 + ((size_t)(b * 12 + l) * NODES + n) * 32;
            const float q1 = q1a[l];
            const float q2 = q1 * q1, q4 = q2 * q2, q8 = q4 * q4;
            float pw[16];
            pw[0] = q1;        pw[1] = q2;        pw[2] = q1 * q2;    pw[3] = q4;
            pw[4] = q1 * q4;   pw[5] = q2 * q4;   pw[6] = pw[2] * q4; pw[7] = q8;
            pw[8] = q1 * q8;   pw[9] = q2 * q8;   pw[10] = pw[2] * q8; pw[11] = q4 * q8;
            pw[12] = pw[4] * q8; pw[13] = pw[5] * q8; pw[14] = pw[6] * q8; pw[15] = q8 * q8;
            float y0 = 0.f, y1 = 0.f, y2 = 0.f, y3 = 0.f;
#pragma unroll
            for (int j = 0; j < 4; ++j) {
                h[j]      = pw[j]      * h[j]      + bc[j]      * dlx;  y0 += h[j]      * bc[16 + j];
                h[j + 4]  = pw[j + 4]  * h[j + 4]  + bc[j + 4]  * dlx;  y1 += h[j + 4]  * bc[20 + j];
                h[j + 8]  = pw[j + 8]  * h[j + 8]  + bc[j + 8]  * dlx;  y2 += h[j + 8]  * bc[24 + j];
                h[j + 12] = pw[j + 12] * h[j + 12] + bc[j + 12] * dlx;  y3 += h[j + 12] * bc[28 + j];
            }
            float y = (y0 + y1) + (y2 + y3);
            y += (float)sc12[l][2] * xsv;
            const float g = y * (float)sc12[l][3] * (float)xq[l];
            s_out[l * 136 + tid] = (__bf16)g;
        }
    } else {
        float As[16];
#pragma unroll
        for (int s = 0; s < 16; ++s) As[s] = -__expf(A_log[e * 16 + s]);
#pragma unroll
        for (int l = 0; l < 12; ++l) {
            const float dl = (float)sc12[l][0], xsv = (float)sc12[l][1];
            const float dlx = dl * xsv;
            const float* bc = bcf32 + ((size_t)(b * 12 + l) * NODES + n) * 32;
            float y = 0.f;
#pragma unroll
            for (int j = 0; j < 16; ++j) {
                const float a = __expf(dl * As[j]);
                h[j] = a * h[j] + bc[j] * dlx;
                y += h[j] * bc[16 + j];
            }
            y += (float)sc12[l][2] * xsv;
            const float g = y * (float)sc12[l][3] * (float)xq[l];
            s_out[l * 136 + tid] = (__bf16)g;
        }
    }
    __syncthreads();

    const int wave = tid >> 6, lane = tid & 63;
    const int lm = lane & 15, lq = lane >> 4;
    const __bf16* Wop = WoSw + (size_t)e * 16384;
    bfx8 a[4];
#pragma unroll
    for (int kc = 0; kc < 4; ++kc)
        a[kc] = *(const bfx8*)(s_out + lm * 136 + kc * 32 + lq * 8);

    f32x4 acc[4];
#pragma unroll
    for (int nt = 0; nt < 4; ++nt) acc[nt] = (f32x4){0.f, 0.f, 0.f, 0.f};
#pragma unroll
    for (int nt = 0; nt < 4; ++nt) {
        const int f = wave * 4 + nt;
#pragma unroll
        for (int kc = 0; kc < 4; ++kc) {
            bfx8 bb = *(const bfx8*)(Wop + ((f * 4 + kc) * 64 + lane) * 8);
            acc[nt] = MFMA16(a[kc], bb, acc[nt]);
        }
    }

    const float bw = blk_w[e], bb2 = blk_b[e];
#pragma unroll
    for (int nt = 0; nt < 4; ++nt) {
        const int col = wave * 64 + nt * 16 + lm;
        const float ob = out_b[e * 128 + col];
#pragma unroll
        for (int r = 0; r < 4; ++r) {
            const int m = lq * 4 + r;
            if (m < 12) {
                const size_t gi = (size_t)row * 1536 + m * 128 + col;
                float vv = bw * (acc[nt][r] + ob) + bb2 + xcur[gi];
                if (last) vv = fsilu(vv);
                xout[gi] = vv;
            }
        }
    }
}

extern "C" void kernel_launch(void* const* d_in, const int* in_sizes, int n_in,
                              void* d_out, int out_size, void* d_ws, size_t ws_size,
                              hipStream_t stream) {
    (void)in_sizes; (void)n_in; (void)out_size; (void)ws_size;
    const float* x_in   = (const float*)d_in[0];
    const float* graph  = (const float*)d_in[1];
    const float* in_w   = (const float*)d_in[2];
    const float* in_b   = (const float*)d_in[3];
    const float* x_w    = (const float*)d_in[4];
    const float* dt_w   = (const float*)d_in[5];
    const float* dt_b   = (const float*)d_in[6];
    const float* A_log  = (const float*)d_in[7];
    const float* out_w  = (const float*)d_in[8];
    const float* out_b  = (const float*)d_in[9];
    const float* fw_r   = (const float*)d_in[10];
    const float* fw_i   = (const float*)d_in[11];
    const float* norm_w = (const float*)d_in[12];
    const float* blk_w  = (const float*)d_in[13];
    const float* blk_b  = (const float*)d_in[14];
    float* out = (float*)d_out;

    float* ws = (float*)d_ws;
    size_t o = 0;
    __bf16* in_w_sw  = (__bf16*)(ws + o); o += 131072 / 2;
    __bf16* x_w_sw   = (__bf16*)(ws + o); o += 98304 / 2;
    __bf16* dtw_sw   = (__bf16*)(ws + o); o += 16384 / 2;
    __bf16* out_w_sw = (__bf16*)(ws + o); o += 65536 / 2;
    __bf16* graph_sw = (__bf16*)(ws + o); o += 1572864 / 2;
    const size_t NE = (size_t)MROWS * 128;
    __bf16* scanp    = (__bf16*)(ws + o); o += (size_t)MROWS * 512 / 2;  // AoS (dl,xs,dp,sz)
    __bf16* xfq_bf   = (__bf16*)(ws + o); o += NE / 2;
    float*  bcf32    = ws + o;            o += (size_t)MROWS * 32;
    float*  mw       = ws + o;            o += 1024;                      // M + w2 per expert

    hipLaunchKernelGGL(k_convert, dim3(7362), dim3(256), 0, stream,
                       in_w, x_w, dt_w, out_w, graph, fw_r, fw_i,
                       in_w_sw, x_w_sw, dtw_sw, out_w_sw, graph_sw, mw);

    for (int e = 0; e < 4; ++e) {
        const float* xcur = (e == 0) ? x_in : (const float*)out;
        const int last = (e == 3) ? 1 : 0;
        hipLaunchKernelGGL(k_fused, dim3(FREQ_BLKS + FUSED2_BLKS), dim3(256), 0, stream,
                           xcur, norm_w, in_w_sw, in_b, x_w_sw, dtw_sw, dt_b, graph_sw,
                           mw, scanp, bcf32, xfq_bf, e);
        hipLaunchKernelGGL(k_scanout, dim3(BN), dim3(128), 0, stream,
                           xcur, scanp, bcf32, xfq_bf, A_log,
                           out_w_sw, out_b, blk_w, blk_b, out, e, last);
    }
}

// Round 17
// 430.110 us; speedup vs baseline: 1.0210x; 1.0210x over previous
//
#include <hip/hip_runtime.h>
#include <math.h>

#define BN    2456
#define LSEQ  12
#define DM    128
#define NODES 307
#define MROWS 29472   // BN * LSEQ
#define FREQ_BLKS  1228
#define FUSED2_BLKS 480   // 96 (b,l) x 5 tiles of 64 nodes

typedef __bf16 bfx8 __attribute__((ext_vector_type(8)));
typedef float  f32x4 __attribute__((ext_vector_type(4)));

#define MFMA16(a, b, c) __builtin_amdgcn_mfma_f32_16x16x32_bf16(a, b, c, 0, 0, 0)

__device__ __forceinline__ float fsilu(float v)     { return v / (1.0f + __expf(-v)); }
__device__ __forceinline__ float fsoftplus(float x) { return fmaxf(x, 0.f) + __logf(1.0f + __expf(-fabsf(x))); }

// ---------------- K0: convert + pre-swizzle weights into MFMA fragment order ----------------
__global__ __launch_bounds__(256)
void k_convert(const float* __restrict__ in_w, const float* __restrict__ x_w,
               const float* __restrict__ dt_w, const float* __restrict__ out_w,
               const float* __restrict__ graph,
               const float* __restrict__ fw_r, const float* __restrict__ fw_i,
               __bf16* __restrict__ in_w_sw, __bf16* __restrict__ x_w_sw,
               __bf16* __restrict__ dtw_sw, __bf16* __restrict__ out_w_sw,
               __bf16* __restrict__ graph_sw, float* __restrict__ mw) {
    int idx = blockIdx.x * 256 + threadIdx.x;
    if (idx < 131072) {            // in_w: 4e x 16nt x 4kc (K=128)
        int o = idx;
        int e = o >> 15, r = o & 32767;
        int frag = r >> 9, lane = (r >> 3) & 63, j = r & 7;
        int nt = frag >> 2, kc = frag & 3, lm = lane & 15, lq = lane >> 4;
        in_w_sw[o] = (__bf16)in_w[e * 32768 + (nt * 16 + lm) * 128 + kc * 32 + lq * 8 + j];
        return;
    }
    idx -= 131072;
    if (idx < 98304) {             // x_w: 4e x 12nt x 4kc (K=128)
        int o = idx;
        int e = o / 24576, r = o - e * 24576;
        int frag = r >> 9, lane = (r >> 3) & 63, j = r & 7;
        int nt = frag >> 2, kc = frag & 3, lm = lane & 15, lq = lane >> 4;
        x_w_sw[o] = (__bf16)x_w[e * 24576 + (nt * 16 + lm) * 128 + kc * 32 + lq * 8 + j];
        return;
    }
    idx -= 98304;
    if (idx < 16384) {             // dt_w: 4e x 8nt (K=32)
        int o = idx;
        int e = o >> 12, r = o & 4095;
        int nt = r >> 9, lane = (r >> 3) & 63, j = r & 7;
        int lm = lane & 15, lq = lane >> 4;
        dtw_sw[o] = (__bf16)dt_w[e * 4096 + (nt * 16 + lm) * 32 + lq * 8 + j];
        return;
    }
    idx -= 16384;
    if (idx < 65536) {             // out_w: 4e x 8nt x 4kc (K=128)
        int o = idx;
        int e = o >> 14, r = o & 16383;
        int frag = r >> 9, lane = (r >> 3) & 63, j = r & 7;
        int f = frag >> 2, kc = frag & 3, lm = lane & 15, lq = lane >> 4;
        out_w_sw[o] = (__bf16)out_w[e * 16384 + (f * 16 + lm) * 128 + kc * 32 + lq * 8 + j];
        return;
    }
    idx -= 65536;
    if (idx < 1572864) {           // graph: coalesced read, fragment-order write
        int bl = idx >> 14, r = idx & 16383;
        int dd = r >> 7, a = r & 127;           // src: graph[bl][dd][a], B rows=K=dd, cols=a
        int nt = a >> 4, lm = a & 15, kc = dd >> 5, lq = (dd >> 3) & 3, j = dd & 7;
        graph_sw[(size_t)bl * 16384 + ((size_t)((nt * 4 + kc) * 64 + lq * 16 + lm)) * 8 + j] =
            (__bf16)graph[(size_t)bl * 16384 + dd * 128 + a];
        return;
    }
    idx -= 1572864;
    if (idx < 336) {               // M = fw[:, :13] . D24  (7x12 complex per expert)
        int o = idx;
        int e = o / 84, r = o - e * 84;
        int o2 = r / 12, l = r - o2 * 12;
        float mr = 0.f, mi = 0.f;
        for (int k = 0; k < 13; ++k) {
            float sv, cv;
            __sincosf(6.283185307179586f * (float)(k * l) / 24.0f, &sv, &cv);
            const float wr = fw_r[e * 133 + o2 * 19 + k], wi = fw_i[e * 133 + o2 * 19 + k];
            mr += wr * cv + wi * sv;
            mi += wi * cv - wr * sv;
        }
        mw[e * 256 + (o2 * 12 + l) * 2]     = mr;
        mw[e * 256 + (o2 * 12 + l) * 2 + 1] = mi;
        return;
    }
    idx -= 336;
    if (idx < 168) {               // w2 copy (7x6 complex per expert)
        int o = idx;
        int e = o / 42, r = o - e * 42;
        int o2 = r / 6, k = r - o2 * 6;
        mw[e * 256 + 168 + (o2 * 6 + k) * 2]     = fw_r[e * 133 + o2 * 19 + 13 + k];
        mw[e * 256 + 168 + (o2 * 6 + k) * 2 + 1] = fw_i[e * 133 + o2 * 19 + 13 + k];
    }
}

// ---------------- K1: {freq rows FIRST} + {fused 64-node GEMM tiles after} ----------------
// (byte-identical to rounds 12/15)
__global__ __launch_bounds__(256)
void k_fused(const float* __restrict__ xcur, const float* __restrict__ norm_w,
             const __bf16* __restrict__ WiSw, const float* __restrict__ in_b,
             const __bf16* __restrict__ WxSw, const __bf16* __restrict__ DWSw,
             const float* __restrict__ dt_b, const __bf16* __restrict__ GSw,
             const float* __restrict__ mw,
             __bf16* __restrict__ dmix_bf, __bf16* __restrict__ xs_bf,
             __bf16* __restrict__ dpf, __bf16* __restrict__ sz_bf,
             float* __restrict__ bcf32, __bf16* __restrict__ xfq_bf, int e) {
    const int tid = threadIdx.x;
    __shared__ __bf16 sxs[4 * 16 * 136];      // phase1 xs; reused as delta in phase3/4
    __shared__ __bf16 sdel32[4 * 16 * 40];

    if (blockIdx.x < FREQ_BLKS) {
        // ================== freq path: 2 rows per block ==================
        float (*sred2)[2][12] = (float (*)[2][12])sxs;
        const int hh = tid >> 7, t7 = tid & 127;
        const int lane = tid & 63, w2 = (tid >> 6) & 1;
        const int row = blockIdx.x * 2 + hh;
        const int b = row / NODES, n = row - b * NODES;

        constexpr float SQ32 = 0.8660254037844386f;
        constexpr float C12[12] = {1.f, SQ32, 0.5f, 0.f, -0.5f, -SQ32, -1.f, -SQ32, -0.5f, 0.f, 0.5f, SQ32};
        constexpr float S12[12] = {0.f, 0.5f, SQ32, 1.f, SQ32, 0.5f, 0.f, -0.5f, -SQ32, -1.f, -SQ32, -0.5f};

        const float* xp = xcur + (size_t)row * 1536 + t7;
        float xv[12], v[12];
#pragma unroll
        for (int l = 0; l < 12; ++l) { xv[l] = xp[l * 128]; v[l] = xv[l] * xv[l]; }
#pragma unroll
        for (int off = 32; off; off >>= 1)
#pragma unroll
            for (int i = 0; i < 12; ++i) v[i] += __shfl_xor(v[i], off, 64);
        if (lane == 0) {
#pragma unroll
            for (int i = 0; i < 12; ++i) sred2[hh][w2][i] = v[i];
        }
        __syncthreads();
#pragma unroll
        for (int i = 0; i < 12; ++i) v[i] = sred2[hh][0][i] + sred2[hh][1][i];
        __syncthreads();

        const float nrmw = norm_w[e * DM + t7];
        float xnr[12];
#pragma unroll
        for (int l = 0; l < 12; ++l)
            xnr[l] = xv[l] * rsqrtf(v[l] * (1.0f / 128.0f) + 1e-5f) * nrmw;

        float fr[7], fi[7];
#pragma unroll
        for (int o2 = 0; o2 < 7; ++o2) {
            float r = 0.f, im = 0.f;
#pragma unroll
            for (int l = 0; l < 12; ++l) {
                const int t = (o2 * l) % 12;
                r += xnr[l] * C12[t];
                im -= xnr[l] * S12[t];
            }
            fr[o2] = r; fi[o2] = im;
        }

        float a7[7];
#pragma unroll
        for (int o2 = 0; o2 < 7; ++o2) {
            const float ar = fr[o2] + 1e-6f, ai = fi[o2] + 1e-6f;
            a7[o2] = ar * ar + ai * ai;
        }
#pragma unroll
        for (int pss = 0; pss < 6; ++pss)
#pragma unroll
            for (int j = 0; j < 6; ++j) {
                const float hi = fmaxf(a7[j], a7[j + 1]);
                const float lo = fminf(a7[j], a7[j + 1]);
                a7[j] = hi; a7[j + 1] = lo;
            }

        const float* Me = mw + e * 256;
        float p7[7];
#pragma unroll
        for (int o2 = 0; o2 < 7; ++o2) {
            float pr = 0.f, pi = 0.f;
#pragma unroll
            for (int l = 0; l < 12; ++l) {
                pr += xnr[l] * Me[(o2 * 12 + l) * 2];
                pi += xnr[l] * Me[(o2 * 12 + l) * 2 + 1];
            }
#pragma unroll
            for (int k = 0; k < 6; ++k) {
                pr += a7[k] * Me[168 + (o2 * 6 + k) * 2];
                pi += a7[k] * Me[168 + (o2 * 6 + k) * 2 + 1];
            }
            p7[o2] = pr * pr + pi * pi;
        }

        float m7[7];
#pragma unroll
        for (int i = 0; i < 7; ++i) m7[i] = p7[i];
#pragma unroll
        for (int off = 32; off; off >>= 1)
#pragma unroll
            for (int i = 0; i < 7; ++i) m7[i] = fmaxf(m7[i], __shfl_xor(m7[i], off, 64));
        if (lane == 0) {
#pragma unroll
            for (int i = 0; i < 7; ++i) sred2[hh][w2][i] = m7[i];
        }
        __syncthreads();
#pragma unroll
        for (int i = 0; i < 7; ++i) m7[i] = fmaxf(sred2[hh][0][i], sred2[hh][1][i]);
        __syncthreads();

        float ex[7], sm[7];
#pragma unroll
        for (int i = 0; i < 7; ++i) { ex[i] = __expf(p7[i] - m7[i]); sm[i] = ex[i]; }
#pragma unroll
        for (int off = 32; off; off >>= 1)
#pragma unroll
            for (int i = 0; i < 7; ++i) sm[i] += __shfl_xor(sm[i], off, 64);
        if (lane == 0) {
#pragma unroll
            for (int i = 0; i < 7; ++i) sred2[hh][w2][i] = sm[i];
        }
        __syncthreads();
#pragma unroll
        for (int i = 0; i < 7; ++i) sm[i] = sred2[hh][0][i] + sred2[hh][1][i];

        float gr[7], gi[7];
#pragma unroll
        for (int o2 = 0; o2 < 7; ++o2) {
            const float wf = ex[o2] / sm[o2];
            gr[o2] = wf * fr[o2];
            gi[o2] = wf * fi[o2];
        }

        const size_t xb = ((size_t)(b * 12) * NODES + n) * 128 + t7;
#pragma unroll
        for (int l = 0; l < 12; ++l) {
            float val = gr[0] + ((l & 1) ? -gr[6] : gr[6]);
#pragma unroll
            for (int o2 = 1; o2 < 6; ++o2) {
                const int t = (o2 * l) % 12;
                val += 2.0f * (gr[o2] * C12[t] - gi[o2] * S12[t]);
            }
            xfq_bf[xb + (size_t)l * (NODES * 128)] = (__bf16)(val * (1.0f / 12.0f));
        }
        return;
    }

    // ================== fused GEMM path: (b,l) x 64 nodes, m-split waves, no barriers ==================
    const int fid = blockIdx.x - FREQ_BLKS;      // 0..479
    const int bl = fid / 5;
    const int n0 = (fid - bl * 5) * 64;
    const int wave = tid >> 6, lane = tid & 63;
    const int lm = lane & 15, lq = lane >> 4;
    const int b = bl / 12, l = bl - b * 12;
    const int nbase = n0 + wave * 16;            // this wave's first node
    const size_t rowbase = (size_t)bl * NODES + nbase;
    __bf16* sxsW = sxs + wave * 16 * 136;        // xs, later delta
    __bf16* sdel32W = sdel32 + wave * 16 * 40;

    // ---- phase 0: rmsnorm -> A fragments (lane's A-row = node nbase+lm) ----
    const int ng = min(nbase + lm, NODES - 1);
    const float* xrow = xcur + ((size_t)(b * NODES + ng) * 12 + l) * 128 + lq * 8;
    float xv[4][8];
#pragma unroll
    for (int kc = 0; kc < 4; ++kc) {
        float4 p0 = *(const float4*)(xrow + kc * 32);
        float4 p1 = *(const float4*)(xrow + kc * 32 + 4);
        xv[kc][0] = p0.x; xv[kc][1] = p0.y; xv[kc][2] = p0.z; xv[kc][3] = p0.w;
        xv[kc][4] = p1.x; xv[kc][5] = p1.y; xv[kc][6] = p1.z; xv[kc][7] = p1.w;
    }
    float ss = 0.f;
#pragma unroll
    for (int kc = 0; kc < 4; ++kc)
#pragma unroll
        for (int j = 0; j < 8; ++j) ss += xv[kc][j] * xv[kc][j];
    ss += __shfl_xor(ss, 16, 64);
    ss += __shfl_xor(ss, 32, 64);
    const float rms = rsqrtf(ss * (1.0f / 128.0f) + 1e-5f);

    bfx8 af[4];
    const float* nwp = norm_w + e * DM + lq * 8;
#pragma unroll
    for (int kc = 0; kc < 4; ++kc) {
        float4 w0 = *(const float4*)(nwp + kc * 32);
        float4 w1 = *(const float4*)(nwp + kc * 32 + 4);
        af[kc][0] = (__bf16)(xv[kc][0] * rms * w0.x);
        af[kc][1] = (__bf16)(xv[kc][1] * rms * w0.y);
        af[kc][2] = (__bf16)(xv[kc][2] * rms * w0.z);
        af[kc][3] = (__bf16)(xv[kc][3] * rms * w0.w);
        af[kc][4] = (__bf16)(xv[kc][4] * rms * w1.x);
        af[kc][5] = (__bf16)(xv[kc][5] * rms * w1.y);
        af[kc][6] = (__bf16)(xv[kc][6] * rms * w1.z);
        af[kc][7] = (__bf16)(xv[kc][7] * rms * w1.w);
    }

    const __bf16* WiP = WiSw + (size_t)e * 32768;
    const f32x4 z4 = {0.f, 0.f, 0.f, 0.f};

    // ---- phase 1a: in_proj cols 0..127 (xs -> LDS + xs plane) ----
    {
        f32x4 acc8[8];
#pragma unroll
        for (int ntl = 0; ntl < 8; ++ntl) acc8[ntl] = z4;
#pragma unroll
        for (int ntl = 0; ntl < 8; ++ntl)
#pragma unroll
            for (int kc = 0; kc < 4; ++kc) {
                bfx8 bb = *(const bfx8*)(WiP + ((ntl * 4 + kc) * 64 + lane) * 8);
                acc8[ntl] = MFMA16(af[kc], bb, acc8[ntl]);
            }
#pragma unroll
        for (int ntl = 0; ntl < 8; ++ntl) {
            const int col = ntl * 16 + lm;
            const float bias = in_b[e * 256 + col];
#pragma unroll
            for (int r = 0; r < 4; ++r) {
                const int nl = lq * 4 + r;
                const float v = fsilu(acc8[ntl][r] + bias);
                sxsW[nl * 136 + col] = (__bf16)v;
                if (nbase + nl < NODES)
                    xs_bf[(rowbase + nl) * 128 + col] = (__bf16)v;
            }
        }
    }
    // ---- phase 1b: in_proj cols 128..255 (z -> silu -> sz plane) ----
    {
        f32x4 acc8[8];
#pragma unroll
        for (int ntl = 0; ntl < 8; ++ntl) acc8[ntl] = z4;
#pragma unroll
        for (int ntl = 0; ntl < 8; ++ntl)
#pragma unroll
            for (int kc = 0; kc < 4; ++kc) {
                bfx8 bb = *(const bfx8*)(WiP + (((ntl + 8) * 4 + kc) * 64 + lane) * 8);
                acc8[ntl] = MFMA16(af[kc], bb, acc8[ntl]);
            }
#pragma unroll
        for (int ntl = 0; ntl < 8; ++ntl) {
            const int col = (ntl + 8) * 16 + lm;           // 128..255
            const float bias = in_b[e * 256 + col];
#pragma unroll
            for (int r = 0; r < 4; ++r) {
                const int nl = lq * 4 + r;
                const float v = fsilu(acc8[ntl][r] + bias);
                if (nbase + nl < NODES)
                    sz_bf[(rowbase + nl) * 128 + (col - 128)] = (__bf16)v;
            }
        }
    }

    // ---- phase 2: x_proj (A = wave's xs from LDS) ----
    {
        bfx8 ax[4];
#pragma unroll
        for (int kc = 0; kc < 4; ++kc)
            ax[kc] = *(const bfx8*)(sxsW + lm * 136 + kc * 32 + lq * 8);

        const __bf16* WxP = WxSw + (size_t)e * 24576;
        f32x4 acc12[12];
#pragma unroll
        for (int ntl = 0; ntl < 12; ++ntl) acc12[ntl] = z4;
#pragma unroll
        for (int ntl = 0; ntl < 12; ++ntl)
#pragma unroll
            for (int kc = 0; kc < 4; ++kc) {
                bfx8 bb = *(const bfx8*)(WxP + ((ntl * 4 + kc) * 64 + lane) * 8);
                acc12[ntl] = MFMA16(ax[kc], bb, acc12[ntl]);
            }
#pragma unroll
        for (int ntl = 0; ntl < 12; ++ntl) {
            const int col = ntl * 16 + lm;                 // 0..191
#pragma unroll
            for (int r = 0; r < 4; ++r) {
                const int nl = lq * 4 + r;
                const float v = acc12[ntl][r];
                const int ok = (nbase + nl) < NODES;
                if (col < 32) sdel32W[nl * 40 + col] = (__bf16)v;
                else if (col < 64) { if (ok) bcf32[(rowbase + nl) * 32 + (col - 32)] = v; }
                else if (ok) dpf[(rowbase + nl) * 128 + (col - 64)] = (__bf16)v;
            }
        }
    }

    // ---- phase 3: dt projection (K=32); delta overwrites sxsW (xs dead) ----
    {
        bfx8 ad = *(const bfx8*)(sdel32W + lm * 40 + lq * 8);
        const __bf16* DWp = DWSw + (size_t)e * 4096;
#pragma unroll
        for (int ntl = 0; ntl < 8; ++ntl) {
            bfx8 bb = *(const bfx8*)(DWp + (ntl * 64 + lane) * 8);
            f32x4 dacc = MFMA16(ad, bb, z4);
            const int col = ntl * 16 + lm;
            const float bias = dt_b[e * 128 + col];
#pragma unroll
            for (int r = 0; r < 4; ++r) {
                const int nl = lq * 4 + r;
                sxsW[nl * 136 + col] = (__bf16)fsoftplus(dacc[r] + bias);
            }
        }
    }

    // ---- phase 4: graph mix -> dmix plane ----
    {
        bfx8 ag[4];
#pragma unroll
        for (int kc = 0; kc < 4; ++kc)
            ag[kc] = *(const bfx8*)(sxsW + lm * 136 + kc * 32 + lq * 8);

        const __bf16* Gp = GSw + (size_t)bl * 16384;
#pragma unroll
        for (int ntl = 0; ntl < 8; ++ntl) {
            f32x4 gacc = z4;
#pragma unroll
            for (int kc = 0; kc < 4; ++kc) {
                bfx8 bb = *(const bfx8*)(Gp + ((ntl * 4 + kc) * 64 + lane) * 8);
                gacc = MFMA16(ag[kc], bb, gacc);
            }
            const int col = ntl * 16 + lm;
#pragma unroll
            for (int r = 0; r < 4; ++r) {
                const int nl = lq * 4 + r;
                if (nbase + nl < NODES)
                    dmix_bf[(rowbase + nl) * 128 + col] = (__bf16)gacc[r];
            }
        }
    }
}

// ---------------- K2: SSM scan + gate + out_proj + residual ----------------
// grid (2456) x 128. One (b,n) row, one d per thread.
// Plane inputs staged into LDS via wide cooperative bfx8 loads; B/C read directly
// from global at block-uniform addresses (compiler scalarizes to s_load -> SGPRs).
__global__ __launch_bounds__(128)
void k_scanout(const float* __restrict__ xcur, const __bf16* __restrict__ dmix_bf,
               const __bf16* __restrict__ xs_bf, const __bf16* __restrict__ dpf,
               const __bf16* __restrict__ sz_bf, const float* __restrict__ bcf32,
               const __bf16* __restrict__ xfq_bf, const float* __restrict__ A_log,
               const __bf16* __restrict__ WoSw, const float* __restrict__ out_b,
               const float* __restrict__ blk_w, const float* __restrict__ blk_b,
               float* __restrict__ xout, int e, int last) {
    __shared__ __bf16 spl[5][12][128];   // 0=dmix 1=xs 2=dp 3=sz 4=xfq
    __shared__ __bf16 s_out[16 * 136];
    const int row = blockIdx.x, tid = threadIdx.x;
    const int b = row / NODES, n = row - b * NODES;

    constexpr float LOGT[16] = {0.f, 0.6931472f, 1.0986123f, 1.3862944f, 1.6094379f, 1.7917595f,
                                1.9459101f, 2.0794415f, 2.1972246f, 2.3025851f, 2.3978953f,
                                2.4849066f, 2.5649494f, 2.6390573f, 2.7080502f, 2.7725887f};

    // ---- cooperative vectorized staging: 5 planes x 12 l x 256B, 16B per lane ----
    const size_t pbase = ((size_t)(b * 12) * NODES + n) * 128;
    const size_t ps = (size_t)NODES * 128;
#pragma unroll
    for (int p = 0; p < 5; ++p) {
        const __bf16* src = (p == 0) ? dmix_bf : (p == 1) ? xs_bf : (p == 2) ? dpf
                          : (p == 3) ? sz_bf : xfq_bf;
        {
            const int c = tid;                 // 0..127 -> l=c>>4, ch8=c&15
            const int l = c >> 4, ch8 = c & 15;
            *(bfx8*)(&spl[p][l][ch8 * 8]) =
                *(const bfx8*)(src + pbase + (size_t)l * ps + ch8 * 8);
        }
        if (tid < 64) {
            const int c = tid + 128;           // 128..191
            const int l = c >> 4, ch8 = c & 15;
            *(bfx8*)(&spl[p][l][ch8 * 8]) =
                *(const bfx8*)(src + pbase + (size_t)l * ps + ch8 * 8);
        }
    }

    int chainOK = 1;
#pragma unroll
    for (int s = 0; s < 16; ++s)
        chainOK &= (fabsf(A_log[e * 16 + s] - LOGT[s]) < 1e-4f) ? 1 : 0;

#pragma unroll
    for (int r = 12; r < 16; ++r) s_out[r * 136 + tid] = (__bf16)0.f;
    __syncthreads();

    // ---- SSM scan: 16 states/thread; planes from LDS, B/C uniform from global ----
    float h[16];
#pragma unroll
    for (int j = 0; j < 16; ++j) h[j] = 0.f;

    if (chainOK) {
        float q1a[12];
#pragma unroll
        for (int l = 0; l < 12; ++l) q1a[l] = __expf(-(float)spl[0][l][tid]);
#pragma unroll
        for (int l = 0; l < 12; ++l) {
            const float dl = (float)spl[0][l][tid], xsv = (float)spl[1][l][tid];
            const float dlx = dl * xsv;
            const float* bc = bcf32 + ((size_t)(b * 12 + l) * NODES + n) * 32;
            const float q1 = q1a[l];
            const float q2 = q1 * q1, q4 = q2 * q2, q8 = q4 * q4;
            float pw[16];
            pw[0] = q1;        pw[1] = q2;        pw[2] = q1 * q2;    pw[3] = q4;
            pw[4] = q1 * q4;   pw[5] = q2 * q4;   pw[6] = pw[2] * q4; pw[7] = q8;
            pw[8] = q1 * q8;   pw[9] = q2 * q8;   pw[10] = pw[2] * q8; pw[11] = q4 * q8;
            pw[12] = pw[4] * q8; pw[13] = pw[5] * q8; pw[14] = pw[6] * q8; pw[15] = q8 * q8;
            float y0 = 0.f, y1 = 0.f, y2 = 0.f, y3 = 0.f;
#pragma unroll
            for (int j = 0; j < 4; ++j) {
                h[j]      = pw[j]      * h[j]      + bc[j]      * dlx;  y0 += h[j]      * bc[16 + j];
                h[j + 4]  = pw[j + 4]  * h[j + 4]  + bc[j + 4]  * dlx;  y1 += h[j + 4]  * bc[20 + j];
                h[j + 8]  = pw[j + 8]  * h[j + 8]  + bc[j + 8]  * dlx;  y2 += h[j + 8]  * bc[24 + j];
                h[j + 12] = pw[j + 12] * h[j + 12] + bc[j + 12] * dlx;  y3 += h[j + 12] * bc[28 + j];
            }
            float y = (y0 + y1) + (y2 + y3);
            y += (float)spl[2][l][tid] * xsv;
            const float g = y * (float)spl[3][l][tid] * (float)spl[4][l][tid];
            s_out[l * 136 + tid] = (__bf16)g;
        }
    } else {
        float As[16];
#pragma unroll
        for (int s = 0; s < 16; ++s) As[s] = -__expf(A_log[e * 16 + s]);
#pragma unroll
        for (int l = 0; l < 12; ++l) {
            const float dl = (float)spl[0][l][tid], xsv = (float)spl[1][l][tid];
            const float dlx = dl * xsv;
            const float* bc = bcf32 + ((size_t)(b * 12 + l) * NODES + n) * 32;
            float y = 0.f;
#pragma unroll
            for (int j = 0; j < 16; ++j) {
                const float a = __expf(dl * As[j]);
                h[j] = a * h[j] + bc[j] * dlx;
                y += h[j] * bc[16 + j];
            }
            y += (float)spl[2][l][tid] * xsv;
            const float g = y * (float)spl[3][l][tid] * (float)spl[4][l][tid];
            s_out[l * 136 + tid] = (__bf16)g;
        }
    }
    __syncthreads();

    // ---- out_proj: N=128 split 64/64 by wave, pre-swizzled weights ----
    const int wave = tid >> 6, lane = tid & 63;
    const int lm = lane & 15, lq = lane >> 4;
    const __bf16* Wop = WoSw + (size_t)e * 16384;
    bfx8 a[4];
#pragma unroll
    for (int kc = 0; kc < 4; ++kc)
        a[kc] = *(const bfx8*)(s_out + lm * 136 + kc * 32 + lq * 8);

    f32x4 acc[4];
#pragma unroll
    for (int nt = 0; nt < 4; ++nt) acc[nt] = (f32x4){0.f, 0.f, 0.f, 0.f};
#pragma unroll
    for (int nt = 0; nt < 4; ++nt) {
        const int f = wave * 4 + nt;
#pragma unroll
        for (int kc = 0; kc < 4; ++kc) {
            bfx8 bb = *(const bfx8*)(Wop + ((f * 4 + kc) * 64 + lane) * 8);
            acc[nt] = MFMA16(a[kc], bb, acc[nt]);
        }
    }

    const float bw = blk_w[e], bb2 = blk_b[e];
#pragma unroll
    for (int nt = 0; nt < 4; ++nt) {
        const int col = wave * 64 + nt * 16 + lm;
        const float ob = out_b[e * 128 + col];
#pragma unroll
        for (int r = 0; r < 4; ++r) {
            const int m = lq * 4 + r;
            if (m < 12) {
                const size_t gi = (size_t)row * 1536 + m * 128 + col;
                float vv = bw * (acc[nt][r] + ob) + bb2 + xcur[gi];
                if (last) vv = fsilu(vv);
                xout[gi] = vv;
            }
        }
    }
}

extern "C" void kernel_launch(void* const* d_in, const int* in_sizes, int n_in,
                              void* d_out, int out_size, void* d_ws, size_t ws_size,
                              hipStream_t stream) {
    (void)in_sizes; (void)n_in; (void)out_size; (void)ws_size;
    const float* x_in   = (const float*)d_in[0];
    const float* graph  = (const float*)d_in[1];
    const float* in_w   = (const float*)d_in[2];
    const float* in_b   = (const float*)d_in[3];
    const float* x_w    = (const float*)d_in[4];
    const float* dt_w   = (const float*)d_in[5];
    const float* dt_b   = (const float*)d_in[6];
    const float* A_log  = (const float*)d_in[7];
    const float* out_w  = (const float*)d_in[8];
    const float* out_b  = (const float*)d_in[9];
    const float* fw_r   = (const float*)d_in[10];
    const float* fw_i   = (const float*)d_in[11];
    const float* norm_w = (const float*)d_in[12];
    const float* blk_w  = (const float*)d_in[13];
    const float* blk_b  = (const float*)d_in[14];
    float* out = (float*)d_out;

    float* ws = (float*)d_ws;
    size_t o = 0;
    __bf16* in_w_sw  = (__bf16*)(ws + o); o += 131072 / 2;
    __bf16* x_w_sw   = (__bf16*)(ws + o); o += 98304 / 2;
    __bf16* dtw_sw   = (__bf16*)(ws + o); o += 16384 / 2;
    __bf16* out_w_sw = (__bf16*)(ws + o); o += 65536 / 2;
    __bf16* graph_sw = (__bf16*)(ws + o); o += 1572864 / 2;
    const size_t NE = (size_t)MROWS * 128;
    __bf16* dmix_bf  = (__bf16*)(ws + o); o += NE / 2;
    __bf16* xs_bf    = (__bf16*)(ws + o); o += NE / 2;
    __bf16* dpf      = (__bf16*)(ws + o); o += NE / 2;
    __bf16* sz_bf    = (__bf16*)(ws + o); o += NE / 2;
    __bf16* xfq_bf   = (__bf16*)(ws + o); o += NE / 2;
    float*  bcf32    = ws + o;            o += (size_t)MROWS * 32;
    float*  mw       = ws + o;            o += 1024;                      // M + w2 per expert

    hipLaunchKernelGGL(k_convert, dim3(7362), dim3(256), 0, stream,
                       in_w, x_w, dt_w, out_w, graph, fw_r, fw_i,
                       in_w_sw, x_w_sw, dtw_sw, out_w_sw, graph_sw, mw);

    for (int e = 0; e < 4; ++e) {
        const float* xcur = (e == 0) ? x_in : (const float*)out;
        const int last = (e == 3) ? 1 : 0;
        hipLaunchKernelGGL(k_fused, dim3(FREQ_BLKS + FUSED2_BLKS), dim3(256), 0, stream,
                           xcur, norm_w, in_w_sw, in_b, x_w_sw, dtw_sw, dt_b, graph_sw,
                           mw, dmix_bf, xs_bf, dpf, sz_bf, bcf32, xfq_bf, e);
        hipLaunchKernelGGL(k_scanout, dim3(BN), dim3(128), 0, stream,
                           xcur, dmix_bf, xs_bf, dpf, sz_bf, bcf32, xfq_bf, A_log,
                           out_w_sw, out_b, blk_w, blk_b, out, e, last);
    }
}

// Round 18
// 398.830 us; speedup vs baseline: 1.1011x; 1.0784x over previous
//
#include <hip/hip_runtime.h>
#include <math.h>

#define BN    2456
#define LSEQ  12
#define DM    128
#define NODES 307
#define MROWS 29472   // BN * LSEQ
#define FREQ_BLKS  1228
#define FUSED2_BLKS 480   // 96 (b,l) x 5 tiles of 64 nodes

typedef __bf16 bfx8 __attribute__((ext_vector_type(8)));
typedef __bf16 bfx4 __attribute__((ext_vector_type(4)));
typedef float  f32x4 __attribute__((ext_vector_type(4)));

#define MFMA16(a, b, c) __builtin_amdgcn_mfma_f32_16x16x32_bf16(a, b, c, 0, 0, 0)

__device__ __forceinline__ float fsilu(float v)     { return v / (1.0f + __expf(-v)); }
__device__ __forceinline__ float fsoftplus(float x) { return fmaxf(x, 0.f) + __logf(1.0f + __expf(-fabsf(x))); }
__device__ __forceinline__ unsigned short bf16bits(float v) {
    __bf16 b = (__bf16)v;
    return __builtin_bit_cast(unsigned short, b);
}

// ---------------- K0: convert + pre-swizzle weights into MFMA fragment order ----------------
__global__ __launch_bounds__(256)
void k_convert(const float* __restrict__ in_w, const float* __restrict__ x_w,
               const float* __restrict__ dt_w, const float* __restrict__ out_w,
               const float* __restrict__ graph,
               const float* __restrict__ fw_r, const float* __restrict__ fw_i,
               __bf16* __restrict__ in_w_sw, __bf16* __restrict__ x_w_sw,
               __bf16* __restrict__ dtw_sw, __bf16* __restrict__ out_w_sw,
               __bf16* __restrict__ graph_sw, float* __restrict__ mw) {
    int idx = blockIdx.x * 256 + threadIdx.x;
    if (idx < 131072) {            // in_w: 4e x 16nt x 4kc (K=128)
        int o = idx;
        int e = o >> 15, r = o & 32767;
        int frag = r >> 9, lane = (r >> 3) & 63, j = r & 7;
        int nt = frag >> 2, kc = frag & 3, lm = lane & 15, lq = lane >> 4;
        in_w_sw[o] = (__bf16)in_w[e * 32768 + (nt * 16 + lm) * 128 + kc * 32 + lq * 8 + j];
        return;
    }
    idx -= 131072;
    if (idx < 98304) {             // x_w: 4e x 12nt x 4kc (K=128)
        int o = idx;
        int e = o / 24576, r = o - e * 24576;
        int frag = r >> 9, lane = (r >> 3) & 63, j = r & 7;
        int nt = frag >> 2, kc = frag & 3, lm = lane & 15, lq = lane >> 4;
        x_w_sw[o] = (__bf16)x_w[e * 24576 + (nt * 16 + lm) * 128 + kc * 32 + lq * 8 + j];
        return;
    }
    idx -= 98304;
    if (idx < 16384) {             // dt_w: 4e x 8nt (K=32)
        int o = idx;
        int e = o >> 12, r = o & 4095;
        int nt = r >> 9, lane = (r >> 3) & 63, j = r & 7;
        int lm = lane & 15, lq = lane >> 4;
        dtw_sw[o] = (__bf16)dt_w[e * 4096 + (nt * 16 + lm) * 32 + lq * 8 + j];
        return;
    }
    idx -= 16384;
    if (idx < 65536) {             // out_w: 4e x 8nt x 4kc (K=128)
        int o = idx;
        int e = o >> 14, r = o & 16383;
        int frag = r >> 9, lane = (r >> 3) & 63, j = r & 7;
        int f = frag >> 2, kc = frag & 3, lm = lane & 15, lq = lane >> 4;
        out_w_sw[o] = (__bf16)out_w[e * 16384 + (f * 16 + lm) * 128 + kc * 32 + lq * 8 + j];
        return;
    }
    idx -= 65536;
    if (idx < 1572864) {           // graph: coalesced read, fragment-order write
        int bl = idx >> 14, r = idx & 16383;
        int dd = r >> 7, a = r & 127;           // src: graph[bl][dd][a], B rows=K=dd, cols=a
        int nt = a >> 4, lm = a & 15, kc = dd >> 5, lq = (dd >> 3) & 3, j = dd & 7;
        graph_sw[(size_t)bl * 16384 + ((size_t)((nt * 4 + kc) * 64 + lq * 16 + lm)) * 8 + j] =
            (__bf16)graph[(size_t)bl * 16384 + dd * 128 + a];
        return;
    }
    idx -= 1572864;
    if (idx < 336) {               // M = fw[:, :13] . D24  (7x12 complex per expert)
        int o = idx;
        int e = o / 84, r = o - e * 84;
        int o2 = r / 12, l = r - o2 * 12;
        float mr = 0.f, mi = 0.f;
        for (int k = 0; k < 13; ++k) {
            float sv, cv;
            __sincosf(6.283185307179586f * (float)(k * l) / 24.0f, &sv, &cv);
            const float wr = fw_r[e * 133 + o2 * 19 + k], wi = fw_i[e * 133 + o2 * 19 + k];
            mr += wr * cv + wi * sv;
            mi += wi * cv - wr * sv;
        }
        mw[e * 256 + (o2 * 12 + l) * 2]     = mr;
        mw[e * 256 + (o2 * 12 + l) * 2 + 1] = mi;
        return;
    }
    idx -= 336;
    if (idx < 168) {               // w2 copy (7x6 complex per expert)
        int o = idx;
        int e = o / 42, r = o - e * 42;
        int o2 = r / 6, k = r - o2 * 6;
        mw[e * 256 + 168 + (o2 * 6 + k) * 2]     = fw_r[e * 133 + o2 * 19 + 13 + k];
        mw[e * 256 + 168 + (o2 * 6 + k) * 2 + 1] = fw_i[e * 133 + o2 * 19 + 13 + k];
    }
}

// ---------------- K1: {freq rows FIRST} + {fused 64-node GEMM tiles after} ----------------
// Fused path: 64-node m-split, 22.5 KB LDS. AoS scanp written register-only:
// phase 2 stores u32 (dp,sz) at d*4+2 (z kept packed in VGPRs from phase 1b);
// phase 4 stores u32 (dl,xs) at d*4+0 (xs kept packed in VGPRs from phase 1a).
__global__ __launch_bounds__(256)
void k_fused(const float* __restrict__ xcur, const float* __restrict__ norm_w,
             const __bf16* __restrict__ WiSw, const float* __restrict__ in_b,
             const __bf16* __restrict__ WxSw, const __bf16* __restrict__ DWSw,
             const float* __restrict__ dt_b, const __bf16* __restrict__ GSw,
             const float* __restrict__ mw,
             __bf16* __restrict__ scanp, float* __restrict__ bcf32,
             __bf16* __restrict__ xfq_bf, int e) {
    const int tid = threadIdx.x;
    __shared__ __bf16 sxs[4 * 16 * 136];      // phase1 xs; reused as delta in phase3/4
    __shared__ __bf16 sdel32[4 * 16 * 40];

    if (blockIdx.x < FREQ_BLKS) {
        // ================== freq path: 2 rows per block ==================
        float (*sred2)[2][12] = (float (*)[2][12])sxs;
        const int hh = tid >> 7, t7 = tid & 127;
        const int lane = tid & 63, w2 = (tid >> 6) & 1;
        const int row = blockIdx.x * 2 + hh;
        const int b = row / NODES, n = row - b * NODES;

        constexpr float SQ32 = 0.8660254037844386f;
        constexpr float C12[12] = {1.f, SQ32, 0.5f, 0.f, -0.5f, -SQ32, -1.f, -SQ32, -0.5f, 0.f, 0.5f, SQ32};
        constexpr float S12[12] = {0.f, 0.5f, SQ32, 1.f, SQ32, 0.5f, 0.f, -0.5f, -SQ32, -1.f, -SQ32, -0.5f};

        const float* xp = xcur + (size_t)row * 1536 + t7;
        float xv[12], v[12];
#pragma unroll
        for (int l = 0; l < 12; ++l) { xv[l] = xp[l * 128]; v[l] = xv[l] * xv[l]; }
#pragma unroll
        for (int off = 32; off; off >>= 1)
#pragma unroll
            for (int i = 0; i < 12; ++i) v[i] += __shfl_xor(v[i], off, 64);
        if (lane == 0) {
#pragma unroll
            for (int i = 0; i < 12; ++i) sred2[hh][w2][i] = v[i];
        }
        __syncthreads();
#pragma unroll
        for (int i = 0; i < 12; ++i) v[i] = sred2[hh][0][i] + sred2[hh][1][i];
        __syncthreads();

        const float nrmw = norm_w[e * DM + t7];
        float xnr[12];
#pragma unroll
        for (int l = 0; l < 12; ++l)
            xnr[l] = xv[l] * rsqrtf(v[l] * (1.0f / 128.0f) + 1e-5f) * nrmw;

        float fr[7], fi[7];
#pragma unroll
        for (int o2 = 0; o2 < 7; ++o2) {
            float r = 0.f, im = 0.f;
#pragma unroll
            for (int l = 0; l < 12; ++l) {
                const int t = (o2 * l) % 12;
                r += xnr[l] * C12[t];
                im -= xnr[l] * S12[t];
            }
            fr[o2] = r; fi[o2] = im;
        }

        float a7[7];
#pragma unroll
        for (int o2 = 0; o2 < 7; ++o2) {
            const float ar = fr[o2] + 1e-6f, ai = fi[o2] + 1e-6f;
            a7[o2] = ar * ar + ai * ai;
        }
#pragma unroll
        for (int pss = 0; pss < 6; ++pss)
#pragma unroll
            for (int j = 0; j < 6; ++j) {
                const float hi = fmaxf(a7[j], a7[j + 1]);
                const float lo = fminf(a7[j], a7[j + 1]);
                a7[j] = hi; a7[j + 1] = lo;
            }

        const float* Me = mw + e * 256;
        float p7[7];
#pragma unroll
        for (int o2 = 0; o2 < 7; ++o2) {
            float pr = 0.f, pi = 0.f;
#pragma unroll
            for (int l = 0; l < 12; ++l) {
                pr += xnr[l] * Me[(o2 * 12 + l) * 2];
                pi += xnr[l] * Me[(o2 * 12 + l) * 2 + 1];
            }
#pragma unroll
            for (int k = 0; k < 6; ++k) {
                pr += a7[k] * Me[168 + (o2 * 6 + k) * 2];
                pi += a7[k] * Me[168 + (o2 * 6 + k) * 2 + 1];
            }
            p7[o2] = pr * pr + pi * pi;
        }

        float m7[7];
#pragma unroll
        for (int i = 0; i < 7; ++i) m7[i] = p7[i];
#pragma unroll
        for (int off = 32; off; off >>= 1)
#pragma unroll
            for (int i = 0; i < 7; ++i) m7[i] = fmaxf(m7[i], __shfl_xor(m7[i], off, 64));
        if (lane == 0) {
#pragma unroll
            for (int i = 0; i < 7; ++i) sred2[hh][w2][i] = m7[i];
        }
        __syncthreads();
#pragma unroll
        for (int i = 0; i < 7; ++i) m7[i] = fmaxf(sred2[hh][0][i], sred2[hh][1][i]);
        __syncthreads();

        float ex[7], sm[7];
#pragma unroll
        for (int i = 0; i < 7; ++i) { ex[i] = __expf(p7[i] - m7[i]); sm[i] = ex[i]; }
#pragma unroll
        for (int off = 32; off; off >>= 1)
#pragma unroll
            for (int i = 0; i < 7; ++i) sm[i] += __shfl_xor(sm[i], off, 64);
        if (lane == 0) {
#pragma unroll
            for (int i = 0; i < 7; ++i) sred2[hh][w2][i] = sm[i];
        }
        __syncthreads();
#pragma unroll
        for (int i = 0; i < 7; ++i) sm[i] = sred2[hh][0][i] + sred2[hh][1][i];

        float gr[7], gi[7];
#pragma unroll
        for (int o2 = 0; o2 < 7; ++o2) {
            const float wf = ex[o2] / sm[o2];
            gr[o2] = wf * fr[o2];
            gi[o2] = wf * fi[o2];
        }

        const size_t xb = ((size_t)(b * 12) * NODES + n) * 128 + t7;
#pragma unroll
        for (int l = 0; l < 12; ++l) {
            float val = gr[0] + ((l & 1) ? -gr[6] : gr[6]);
#pragma unroll
            for (int o2 = 1; o2 < 6; ++o2) {
                const int t = (o2 * l) % 12;
                val += 2.0f * (gr[o2] * C12[t] - gi[o2] * S12[t]);
            }
            xfq_bf[xb + (size_t)l * (NODES * 128)] = (__bf16)(val * (1.0f / 12.0f));
        }
        return;
    }

    // ================== fused GEMM path: (b,l) x 64 nodes, m-split waves, no barriers ==================
    const int fid = blockIdx.x - FREQ_BLKS;      // 0..479
    const int bl = fid / 5;
    const int n0 = (fid - bl * 5) * 64;
    const int wave = tid >> 6, lane = tid & 63;
    const int lm = lane & 15, lq = lane >> 4;
    const int b = bl / 12, l = bl - b * 12;
    const int nbase = n0 + wave * 16;            // this wave's first node
    const size_t rowbase = (size_t)bl * NODES + nbase;
    __bf16* sxsW = sxs + wave * 16 * 136;        // xs, later delta
    __bf16* sdel32W = sdel32 + wave * 16 * 40;

    // ---- phase 0: rmsnorm -> A fragments (lane's A-row = node nbase+lm) ----
    const int ng = min(nbase + lm, NODES - 1);
    const float* xrow = xcur + ((size_t)(b * NODES + ng) * 12 + l) * 128 + lq * 8;
    float xv[4][8];
#pragma unroll
    for (int kc = 0; kc < 4; ++kc) {
        float4 p0 = *(const float4*)(xrow + kc * 32);
        float4 p1 = *(const float4*)(xrow + kc * 32 + 4);
        xv[kc][0] = p0.x; xv[kc][1] = p0.y; xv[kc][2] = p0.z; xv[kc][3] = p0.w;
        xv[kc][4] = p1.x; xv[kc][5] = p1.y; xv[kc][6] = p1.z; xv[kc][7] = p1.w;
    }
    float ss = 0.f;
#pragma unroll
    for (int kc = 0; kc < 4; ++kc)
#pragma unroll
        for (int j = 0; j < 8; ++j) ss += xv[kc][j] * xv[kc][j];
    ss += __shfl_xor(ss, 16, 64);
    ss += __shfl_xor(ss, 32, 64);
    const float rms = rsqrtf(ss * (1.0f / 128.0f) + 1e-5f);

    bfx8 af[4];
    const float* nwp = norm_w + e * DM + lq * 8;
#pragma unroll
    for (int kc = 0; kc < 4; ++kc) {
        float4 w0 = *(const float4*)(nwp + kc * 32);
        float4 w1 = *(const float4*)(nwp + kc * 32 + 4);
        af[kc][0] = (__bf16)(xv[kc][0] * rms * w0.x);
        af[kc][1] = (__bf16)(xv[kc][1] * rms * w0.y);
        af[kc][2] = (__bf16)(xv[kc][2] * rms * w0.z);
        af[kc][3] = (__bf16)(xv[kc][3] * rms * w0.w);
        af[kc][4] = (__bf16)(xv[kc][4] * rms * w1.x);
        af[kc][5] = (__bf16)(xv[kc][5] * rms * w1.y);
        af[kc][6] = (__bf16)(xv[kc][6] * rms * w1.z);
        af[kc][7] = (__bf16)(xv[kc][7] * rms * w1.w);
    }

    const __bf16* WiP = WiSw + (size_t)e * 32768;
    const f32x4 z4 = {0.f, 0.f, 0.f, 0.f};

    unsigned xsp[8][2];   // packed xs bf16 pairs (r even|odd), kept to phase 4
    unsigned zp[8][2];    // packed z  bf16 pairs, kept to phase 2

    // ---- phase 1a: in_proj cols 0..127 (xs -> LDS + regs) ----
    {
        f32x4 acc8[8];
#pragma unroll
        for (int ntl = 0; ntl < 8; ++ntl) acc8[ntl] = z4;
#pragma unroll
        for (int ntl = 0; ntl < 8; ++ntl)
#pragma unroll
            for (int kc = 0; kc < 4; ++kc) {
                bfx8 bb = *(const bfx8*)(WiP + ((ntl * 4 + kc) * 64 + lane) * 8);
                acc8[ntl] = MFMA16(af[kc], bb, acc8[ntl]);
            }
#pragma unroll
        for (int ntl = 0; ntl < 8; ++ntl) {
            const int col = ntl * 16 + lm;
            const float bias = in_b[e * 256 + col];
            unsigned short h16[4];
#pragma unroll
            for (int r = 0; r < 4; ++r) {
                const int nl = lq * 4 + r;
                const float v = fsilu(acc8[ntl][r] + bias);
                h16[r] = bf16bits(v);
                sxsW[nl * 136 + col] = __builtin_bit_cast(__bf16, h16[r]);
            }
            xsp[ntl][0] = (unsigned)h16[0] | ((unsigned)h16[1] << 16);
            xsp[ntl][1] = (unsigned)h16[2] | ((unsigned)h16[3] << 16);
        }
    }
    // ---- phase 1b: in_proj cols 128..255 (z -> silu -> regs only) ----
    {
        f32x4 acc8[8];
#pragma unroll
        for (int ntl = 0; ntl < 8; ++ntl) acc8[ntl] = z4;
#pragma unroll
        for (int ntl = 0; ntl < 8; ++ntl)
#pragma unroll
            for (int kc = 0; kc < 4; ++kc) {
                bfx8 bb = *(const bfx8*)(WiP + (((ntl + 8) * 4 + kc) * 64 + lane) * 8);
                acc8[ntl] = MFMA16(af[kc], bb, acc8[ntl]);
            }
#pragma unroll
        for (int ntl = 0; ntl < 8; ++ntl) {
            const int col = ntl * 16 + lm;                 // z col 0..127
            const float bias = in_b[e * 256 + 128 + col];
            unsigned short h16[4];
#pragma unroll
            for (int r = 0; r < 4; ++r)
                h16[r] = bf16bits(fsilu(acc8[ntl][r] + bias));
            zp[ntl][0] = (unsigned)h16[0] | ((unsigned)h16[1] << 16);
            zp[ntl][1] = (unsigned)h16[2] | ((unsigned)h16[3] << 16);
        }
    }

    // ---- phase 2: x_proj; epilogue stores (dp,sz) u32 at d*4+2 ----
    {
        bfx8 ax[4];
#pragma unroll
        for (int kc = 0; kc < 4; ++kc)
            ax[kc] = *(const bfx8*)(sxsW + lm * 136 + kc * 32 + lq * 8);

        const __bf16* WxP = WxSw + (size_t)e * 24576;
        f32x4 acc12[12];
#pragma unroll
        for (int ntl = 0; ntl < 12; ++ntl) acc12[ntl] = z4;
#pragma unroll
        for (int ntl = 0; ntl < 12; ++ntl)
#pragma unroll
            for (int kc = 0; kc < 4; ++kc) {
                bfx8 bb = *(const bfx8*)(WxP + ((ntl * 4 + kc) * 64 + lane) * 8);
                acc12[ntl] = MFMA16(ax[kc], bb, acc12[ntl]);
            }
#pragma unroll
        for (int ntl = 0; ntl < 12; ++ntl) {
            const int col = ntl * 16 + lm;                 // 0..191
#pragma unroll
            for (int r = 0; r < 4; ++r) {
                const int nl = lq * 4 + r;
                const float v = acc12[ntl][r];
                const int ok = (nbase + nl) < NODES;
                if (col < 32) sdel32W[nl * 40 + col] = (__bf16)v;
                else if (col < 64) { if (ok) bcf32[(rowbase + nl) * 32 + (col - 32)] = v; }
                else if (ok) {
                    const int d = col - 64;                // dp channel index
                    const unsigned zbits = (zp[ntl - 4][r >> 1] >> ((r & 1) * 16)) & 0xffffu;
                    const unsigned pk = (unsigned)bf16bits(v) | (zbits << 16);
                    *(unsigned*)(scanp + (rowbase + nl) * 512 + d * 4 + 2) = pk;
                }
            }
        }
    }

    // ---- phase 3: dt projection (K=32); delta overwrites sxsW (xs LDS dead) ----
    {
        bfx8 ad = *(const bfx8*)(sdel32W + lm * 40 + lq * 8);
        const __bf16* DWp = DWSw + (size_t)e * 4096;
#pragma unroll
        for (int ntl = 0; ntl < 8; ++ntl) {
            bfx8 bb = *(const bfx8*)(DWp + (ntl * 64 + lane) * 8);
            f32x4 dacc = MFMA16(ad, bb, z4);
            const int col = ntl * 16 + lm;
            const float bias = dt_b[e * 128 + col];
#pragma unroll
            for (int r = 0; r < 4; ++r) {
                const int nl = lq * 4 + r;
                sxsW[nl * 136 + col] = (__bf16)fsoftplus(dacc[r] + bias);
            }
        }
    }

    // ---- phase 4: graph mix; epilogue stores (dl,xs) u32 at d*4+0 ----
    {
        bfx8 ag[4];
#pragma unroll
        for (int kc = 0; kc < 4; ++kc)
            ag[kc] = *(const bfx8*)(sxsW + lm * 136 + kc * 32 + lq * 8);

        const __bf16* Gp = GSw + (size_t)bl * 16384;
#pragma unroll
        for (int ntl = 0; ntl < 8; ++ntl) {
            f32x4 gacc = z4;
#pragma unroll
            for (int kc = 0; kc < 4; ++kc) {
                bfx8 bb = *(const bfx8*)(Gp + ((ntl * 4 + kc) * 64 + lane) * 8);
                gacc = MFMA16(ag[kc], bb, gacc);
            }
            const int d = ntl * 16 + lm;
#pragma unroll
            for (int r = 0; r < 4; ++r) {
                const int nl = lq * 4 + r;
                if (nbase + nl < NODES) {
                    const unsigned xbits = (xsp[ntl][r >> 1] >> ((r & 1) * 16)) & 0xffffu;
                    const unsigned pk = (unsigned)bf16bits(gacc[r]) | (xbits << 16);
                    *(unsigned*)(scanp + (rowbase + nl) * 512 + d * 4 + 0) = pk;
                }
            }
        }
    }
}

// ---------------- K2: SSM scan + gate + out_proj + residual (round-4 AoS, measured 24.6us) ----------------
__global__ __launch_bounds__(128)
void k_scanout(const float* __restrict__ xcur, const __bf16* __restrict__ scanp,
               const float* __restrict__ bcf32, const __bf16* __restrict__ xfq_bf,
               const float* __restrict__ A_log, const __bf16* __restrict__ WoSw,
               const float* __restrict__ out_b, const float* __restrict__ blk_w,
               const float* __restrict__ blk_b, float* __restrict__ xout, int e, int last) {
    __shared__ __bf16 s_out[16 * 136];
    const int row = blockIdx.x, tid = threadIdx.x;
    const int b = row / NODES, n = row - b * NODES;

    constexpr float LOGT[16] = {0.f, 0.6931472f, 1.0986123f, 1.3862944f, 1.6094379f, 1.7917595f,
                                1.9459101f, 2.0794415f, 2.1972246f, 2.3025851f, 2.3978953f,
                                2.4849066f, 2.5649494f, 2.6390573f, 2.7080502f, 2.7725887f};

    // ---- hoisted loads ----
    bfx4 sc12[12];
    const size_t sb = ((size_t)(b * 12) * NODES + n) * 512 + (size_t)tid * 4;
#pragma unroll
    for (int l = 0; l < 12; ++l)
        sc12[l] = *(const bfx4*)(scanp + sb + (size_t)l * (NODES * 512));

    __bf16 xq[12];
    const size_t xb = ((size_t)(b * 12) * NODES + n) * 128 + tid;
#pragma unroll
    for (int l = 0; l < 12; ++l)
        xq[l] = xfq_bf[xb + (size_t)l * (NODES * 128)];

    int chainOK = 1;
#pragma unroll
    for (int s = 0; s < 16; ++s)
        chainOK &= (fabsf(A_log[e * 16 + s] - LOGT[s]) < 1e-4f) ? 1 : 0;

#pragma unroll
    for (int r = 12; r < 16; ++r) s_out[r * 136 + tid] = (__bf16)0.f;

    float h[16];
#pragma unroll
    for (int j = 0; j < 16; ++j) h[j] = 0.f;

    if (chainOK) {
        float q1a[12];
#pragma unroll
        for (int l = 0; l < 12; ++l) q1a[l] = __expf(-(float)sc12[l][0]);
#pragma unroll
        for (int l = 0; l < 12; ++l) {
            const float dl = (float)sc12[l][0], xsv = (float)sc12[l][1];
            const float dlx = dl * xsv;
            const float* bc = bcf32 + ((size_t)(b * 12 + l) * NODES + n) * 32;
            const float q1 = q1a[l];
            const float q2 = q1 * q1, q4 = q2 * q2, q8 = q4 * q4;
            float pw[16];
            pw[0] = q1;        pw[1] = q2;        pw[2] = q1 * q2;    pw[3] = q4;
            pw[4] = q1 * q4;   pw[5] = q2 * q4;   pw[6] = pw[2] * q4; pw[7] = q8;
            pw[8] = q1 * q8;   pw[9] = q2 * q8;   pw[10] = pw[2] * q8; pw[11] = q4 * q8;
            pw[12] = pw[4] * q8; pw[13] = pw[5] * q8; pw[14] = pw[6] * q8; pw[15] = q8 * q8;
            float y0 = 0.f, y1 = 0.f, y2 = 0.f, y3 = 0.f;
#pragma unroll
            for (int j = 0; j < 4; ++j) {
                h[j]      = pw[j]      * h[j]      + bc[j]      * dlx;  y0 += h[j]      * bc[16 + j];
                h[j + 4]  = pw[j + 4]  * h[j + 4]  + bc[j + 4]  * dlx;  y1 += h[j + 4]  * bc[20 + j];
                h[j + 8]  = pw[j + 8]  * h[j + 8]  + bc[j + 8]  * dlx;  y2 += h[j + 8]  * bc[24 + j];
                h[j + 12] = pw[j + 12] * h[j + 12] + bc[j + 12] * dlx;  y3 += h[j + 12] * bc[28 + j];
            }
            float y = (y0 + y1) + (y2 + y3);
            y += (float)sc12[l][2] * xsv;
            const float g = y * (float)sc12[l][3] * (float)xq[l];
            s_out[l * 136 + tid] = (__bf16)g;
        }
    } else {
        float As[16];
#pragma unroll
        for (int s = 0; s < 16; ++s) As[s] = -__expf(A_log[e * 16 + s]);
#pragma unroll
        for (int l = 0; l < 12; ++l) {
            const float dl = (float)sc12[l][0], xsv = (float)sc12[l][1];
            const float dlx = dl * xsv;
            const float* bc = bcf32 + ((size_t)(b * 12 + l) * NODES + n) * 32;
            float y = 0.f;
#pragma unroll
            for (int j = 0; j < 16; ++j) {
                const float a = __expf(dl * As[j]);
                h[j] = a * h[j] + bc[j] * dlx;
                y += h[j] * bc[16 + j];
            }
            y += (float)sc12[l][2] * xsv;
            const float g = y * (float)sc12[l][3] * (float)xq[l];
            s_out[l * 136 + tid] = (__bf16)g;
        }
    }
    __syncthreads();

    const int wave = tid >> 6, lane = tid & 63;
    const int lm = lane & 15, lq = lane >> 4;
    const __bf16* Wop = WoSw + (size_t)e * 16384;
    bfx8 a[4];
#pragma unroll
    for (int kc = 0; kc < 4; ++kc)
        a[kc] = *(const bfx8*)(s_out + lm * 136 + kc * 32 + lq * 8);

    f32x4 acc[4];
#pragma unroll
    for (int nt = 0; nt < 4; ++nt) acc[nt] = (f32x4){0.f, 0.f, 0.f, 0.f};
#pragma unroll
    for (int nt = 0; nt < 4; ++nt) {
        const int f = wave * 4 + nt;
#pragma unroll
        for (int kc = 0; kc < 4; ++kc) {
            bfx8 bb = *(const bfx8*)(Wop + ((f * 4 + kc) * 64 + lane) * 8);
            acc[nt] = MFMA16(a[kc], bb, acc[nt]);
        }
    }

    const float bw = blk_w[e], bb2 = blk_b[e];
#pragma unroll
    for (int nt = 0; nt < 4; ++nt) {
        const int col = wave * 64 + nt * 16 + lm;
        const float ob = out_b[e * 128 + col];
#pragma unroll
        for (int r = 0; r < 4; ++r) {
            const int m = lq * 4 + r;
            if (m < 12) {
                const size_t gi = (size_t)row * 1536 + m * 128 + col;
                float vv = bw * (acc[nt][r] + ob) + bb2 + xcur[gi];
                if (last) vv = fsilu(vv);
                xout[gi] = vv;
            }
        }
    }
}

extern "C" void kernel_launch(void* const* d_in, const int* in_sizes, int n_in,
                              void* d_out, int out_size, void* d_ws, size_t ws_size,
                              hipStream_t stream) {
    (void)in_sizes; (void)n_in; (void)out_size; (void)ws_size;
    const float* x_in   = (const float*)d_in[0];
    const float* graph  = (const float*)d_in[1];
    const float* in_w   = (const float*)d_in[2];
    const float* in_b   = (const float*)d_in[3];
    const float* x_w    = (const float*)d_in[4];
    const float* dt_w   = (const float*)d_in[5];
    const float* dt_b   = (const float*)d_in[6];
    const float* A_log  = (const float*)d_in[7];
    const float* out_w  = (const float*)d_in[8];
    const float* out_b  = (const float*)d_in[9];
    const float* fw_r   = (const float*)d_in[10];
    const float* fw_i   = (const float*)d_in[11];
    const float* norm_w = (const float*)d_in[12];
    const float* blk_w  = (const float*)d_in[13];
    const float* blk_b  = (const float*)d_in[14];
    float* out = (float*)d_out;

    float* ws = (float*)d_ws;
    size_t o = 0;
    __bf16* in_w_sw  = (__bf16*)(ws + o); o += 131072 / 2;
    __bf16* x_w_sw   = (__bf16*)(ws + o); o += 98304 / 2;
    __bf16* dtw_sw   = (__bf16*)(ws + o); o += 16384 / 2;
    __bf16* out_w_sw = (__bf16*)(ws + o); o += 65536 / 2;
    __bf16* graph_sw = (__bf16*)(ws + o); o += 1572864 / 2;
    const size_t NE = (size_t)MROWS * 128;
    __bf16* scanp    = (__bf16*)(ws + o); o += (size_t)MROWS * 512 / 2;  // AoS (dl,xs,dp,sz)
    __bf16* xfq_bf   = (__bf16*)(ws + o); o += NE / 2;
    float*  bcf32    = ws + o;            o += (size_t)MROWS * 32;
    float*  mw       = ws + o;            o += 1024;                      // M + w2 per expert

    hipLaunchKernelGGL(k_convert, dim3(7362), dim3(256), 0, stream,
                       in_w, x_w, dt_w, out_w, graph, fw_r, fw_i,
                       in_w_sw, x_w_sw, dtw_sw, out_w_sw, graph_sw, mw);

    for (int e = 0; e < 4; ++e) {
        const float* xcur = (e == 0) ? x_in : (const float*)out;
        const int last = (e == 3) ? 1 : 0;
        hipLaunchKernelGGL(k_fused, dim3(FREQ_BLKS + FUSED2_BLKS), dim3(256), 0, stream,
                           xcur, norm_w, in_w_sw, in_b, x_w_sw, dtw_sw, dt_b, graph_sw,
                           mw, scanp, bcf32, xfq_bf, e);
        hipLaunchKernelGGL(k_scanout, dim3(BN), dim3(128), 0, stream,
                           xcur, scanp, bcf32, xfq_bf, A_log,
                           out_w_sw, out_b, blk_w, blk_b, out, e, last);
    }
}